// Round 4
// baseline (5518.623 us; speedup 1.0000x reference)
//
#include <hip/hip_runtime.h>

#define NTIME 30
#define NB 4096

typedef __attribute__((ext_vector_type(8))) short short8;
typedef __attribute__((ext_vector_type(4))) float f32x4;

__device__ __forceinline__ unsigned short f2b(float f) {
    unsigned int u = __float_as_uint(f);
    u = u + 0x7FFFu + ((u >> 16) & 1u);        // RNE to bf16
    return (unsigned short)(u >> 16);
}
__device__ __forceinline__ float b2f(unsigned short s) {
    return __uint_as_float(((unsigned int)s) << 16);
}
__device__ __forceinline__ float sigf(float x)     { return 1.0f / (1.0f + __expf(-x)); }
__device__ __forceinline__ float tanhfast(float x) { return 1.0f - 2.0f / (__expf(2.0f * x) + 1.0f); }

// Pack W rows (gate-major, PyTorch i,f,g,o) into MFMA B-fragment stream, bf16 hi/lo planes.
// B-frag for 16x16x32: lane holds B[k = (lane>>4)*8 + j][n = lane&15], j=0..7.
// Block layout: out[(((ks*UG + ug)*4 + g)*2 + plane)*512 + lane*8 + j]  (ushorts)
__global__ void prep_w(const float* __restrict__ Wih, const float* __restrict__ Whh,
                       unsigned short* __restrict__ out,
                       int H, int KIr, int KIp, int KH, int UG, int KS)
{
    int e = blockIdx.x * 256 + threadIdx.x;
    int total = KS * UG * 4 * 2 * 512;
    if (e >= total) return;
    int j     = e & 7;
    int lane  = (e >> 3) & 63;
    int plane = (e >> 9) & 1;
    int g     = (e >> 10) & 3;
    int x     = e >> 12;
    int ug    = x % UG;
    int ks    = x / UG;
    int n = lane & 15, q = lane >> 4;
    int k   = ks * 32 + q * 8 + j;
    int row = g * H + ug * 16 + n;
    float w = 0.0f;
    if (k < KIp) { if (k < KIr) w = Wih[row * KIr + k]; }
    else         { w = Whh[row * KH + (k - KIp)]; }
    unsigned short hi = f2b(w);
    out[e] = plane ? f2b(w - b2f(hi)) : hi;
}

// Fused 3-layer LSTM, MFMA bf16 hi/lo (3-product split precision).
// 256 WGs x 512 thr (8 waves), BT=32 rows/WG, 1 WG/CU, 100KB dynamic LDS.
// launch_bounds(512,2): 2 waves/SIMD -> 256-VGPR budget so B-fragments batch in regs (MLP).
__global__ __launch_bounds__(512, 2) void lstm3_mfma(
    const float* __restrict__ x1, const float* __restrict__ x2,
    const unsigned short* __restrict__ l1w, const unsigned short* __restrict__ l2w,
    const unsigned short* __restrict__ l3w,
    const float* __restrict__ b1, const float* __restrict__ b2, const float* __restrict__ b3,
    float* __restrict__ Y3)
{
    extern __shared__ unsigned short sm[];
    unsigned short* h1hi = sm;                    // 32 rows x 520
    unsigned short* h1lo = h1hi + 32 * 520;
    unsigned short* h2hi = h1lo + 32 * 520;       // 32 x 136
    unsigned short* h2lo = h2hi + 32 * 136;
    unsigned short* h3hi = h2lo + 32 * 136;       // 32 x 72
    unsigned short* h3lo = h3hi + 32 * 72;
    unsigned short* xhi  = h3lo + 32 * 72;        // 32 x 72
    unsigned short* xlo  = xhi  + 32 * 72;

    const int tid  = threadIdx.x;
    const int wv   = tid >> 6;
    const int lane = tid & 63;
    const int nrow = lane & 15;
    const int quad = lane >> 4;

    const int wg  = blockIdx.x;
    const float* __restrict__ Xp = (wg < 128) ? x1 : x2;
    const int row0 = (wg & 127) * 32;
    const int gr0  = wg * 32;

    {
        unsigned int* p = (unsigned int*)sm;
        const int nu32 = (2 * (32 * 520) + 2 * (32 * 136) + 2 * (32 * 72)) / 2;
        for (int i = tid; i < nu32; i += 512) p[i] = 0u;
    }

    float b1v[4][4], b2v[4], b3v[4];
    #pragma unroll
    for (int i = 0; i < 4; ++i)
        #pragma unroll
        for (int g = 0; g < 4; ++g)
            b1v[i][g] = b1[g * 512 + (wv * 4 + i) * 16 + nrow];
    #pragma unroll
    for (int g = 0; g < 4; ++g) b2v[g] = b2[g * 128 + wv * 16 + nrow];
    #pragma unroll
    for (int g = 0; g < 4; ++g) b3v[g] = b3[g * 64 + (wv & 3) * 16 + nrow];

    float c1[2][4][4];
    float c2[2][4];
    float c3[4];
    #pragma unroll
    for (int mt = 0; mt < 2; ++mt)
        #pragma unroll
        for (int i = 0; i < 4; ++i)
            #pragma unroll
            for (int r = 0; r < 4; ++r) c1[mt][i][r] = 0.0f;
    #pragma unroll
    for (int mt = 0; mt < 2; ++mt)
        #pragma unroll
        for (int r = 0; r < 4; ++r) c2[mt][r] = 0.0f;
    #pragma unroll
    for (int r = 0; r < 4; ++r) c3[r] = 0.0f;

    const unsigned short* B1 = l1w + wv * 4 * 4096 + lane * 8;
    const unsigned short* B2 = l2w + wv * 4096 + lane * 8;
    const unsigned short* B3 = l3w + (wv & 3) * 4096 + lane * 8;
    const int mt3 = wv >> 2;

    __syncthreads();

    #pragma unroll 1
    for (int t = 0; t < NTIME; ++t) {
        const bool rev = (t & 1);

        // stage x_t (layout [B,F=58,T=30]) as bf16 hi/lo, K padded to 64
        for (int e = tid; e < 32 * 64; e += 512) {
            int b = e >> 6, f = e & 63;
            float v = (f < 58) ? Xp[(row0 + b) * 1740 + f * 30 + t] : 0.0f;
            unsigned short hi = f2b(v);
            xhi[b * 72 + f] = hi;
            xlo[b * 72 + f] = f2b(v - b2f(hi));
        }
        __syncthreads();   // A: x staged; prev-step h writes visible

        // ================= L1 (k = [x 64 ; h1 512], 18 ksteps) =================
        f32x4 acc[2][4][4];
        #pragma unroll
        for (int mt = 0; mt < 2; ++mt)
            #pragma unroll
            for (int i = 0; i < 4; ++i)
                #pragma unroll
                for (int g = 0; g < 4; ++g) {
                    float b = b1v[i][g];
                    f32x4 v = {b, b, b, b};
                    acc[mt][i][g] = v;
                }

        #pragma unroll 1
        for (int kk = 0; kk < 18; ++kk) {
            int ks = rev ? (17 - kk) : kk;
            short8 ahi[2], alo[2];
            if (ks < 2) {
                int off = ks * 32 + quad * 8;
                ahi[0] = *(const short8*)(xhi + nrow * 72 + off);
                ahi[1] = *(const short8*)(xhi + (16 + nrow) * 72 + off);
                alo[0] = *(const short8*)(xlo + nrow * 72 + off);
                alo[1] = *(const short8*)(xlo + (16 + nrow) * 72 + off);
            } else {
                int off = (ks - 2) * 32 + quad * 8;
                ahi[0] = *(const short8*)(h1hi + nrow * 520 + off);
                ahi[1] = *(const short8*)(h1hi + (16 + nrow) * 520 + off);
                alo[0] = *(const short8*)(h1lo + nrow * 520 + off);
                alo[1] = *(const short8*)(h1lo + (16 + nrow) * 520 + off);
            }
            const unsigned short* bb = B1 + ks * 131072;
            #pragma unroll
            for (int ip = 0; ip < 2; ++ip) {
                // batch 16 B-fragment loads into registers, then the MFMA group
                short8 bh[8], bl[8];
                #pragma unroll
                for (int ii = 0; ii < 2; ++ii)
                    #pragma unroll
                    for (int g = 0; g < 4; ++g) {
                        const unsigned short* p = bb + (ip * 2 + ii) * 4096 + g * 1024;
                        bh[ii * 4 + g] = *(const short8*)p;
                        bl[ii * 4 + g] = *(const short8*)(p + 512);
                    }
                #pragma unroll
                for (int ii = 0; ii < 2; ++ii)
                    #pragma unroll
                    for (int g = 0; g < 4; ++g) {
                        const int i = ip * 2 + ii, xbi = ii * 4 + g;
                        #pragma unroll
                        for (int mt = 0; mt < 2; ++mt) {
                            acc[mt][i][g] = __builtin_amdgcn_mfma_f32_16x16x32_bf16(ahi[mt], bh[xbi], acc[mt][i][g], 0, 0, 0);
                            acc[mt][i][g] = __builtin_amdgcn_mfma_f32_16x16x32_bf16(alo[mt], bh[xbi], acc[mt][i][g], 0, 0, 0);
                            acc[mt][i][g] = __builtin_amdgcn_mfma_f32_16x16x32_bf16(ahi[mt], bl[xbi], acc[mt][i][g], 0, 0, 0);
                        }
                    }
            }
        }
        __syncthreads();   // B: reads of h1(t-1)/x complete
        #pragma unroll
        for (int mt = 0; mt < 2; ++mt)
            #pragma unroll
            for (int i = 0; i < 4; ++i)
                #pragma unroll
                for (int r = 0; r < 4; ++r) {
                    float I = sigf(acc[mt][i][0][r]);
                    float F = sigf(acc[mt][i][1][r]);
                    float G = tanhfast(acc[mt][i][2][r]);
                    float O = sigf(acc[mt][i][3][r]);
                    float c = F * c1[mt][i][r] + I * G;
                    c1[mt][i][r] = c;
                    float h = O * tanhfast(c);
                    int m = mt * 16 + quad * 4 + r;
                    int u = (wv * 4 + i) * 16 + nrow;
                    unsigned short hh = f2b(h);
                    h1hi[m * 520 + u] = hh;
                    h1lo[m * 520 + u] = f2b(h - b2f(hh));
                }
        __syncthreads();   // C: h1(t) visible

        // ================= L2 (k = [relu(h1) 512 ; h2 128], 20 ksteps) =================
        f32x4 a2[2][4];
        #pragma unroll
        for (int mt = 0; mt < 2; ++mt)
            #pragma unroll
            for (int g = 0; g < 4; ++g) {
                float b = b2v[g];
                f32x4 v = {b, b, b, b};
                a2[mt][g] = v;
            }

        #pragma unroll 1
        for (int kk = 0; kk < 20; ++kk) {
            int ks = rev ? (19 - kk) : kk;
            short8 ahi[2], alo[2];
            if (ks < 16) {
                int off = ks * 32 + quad * 8;
                #pragma unroll
                for (int mt = 0; mt < 2; ++mt) {
                    short8 a  = *(const short8*)(h1hi + (mt * 16 + nrow) * 520 + off);
                    short8 al = *(const short8*)(h1lo + (mt * 16 + nrow) * 520 + off);
                    short8 msk = a >> 15;
                    ahi[mt] = a & ~msk;
                    alo[mt] = al & ~msk;
                }
            } else {
                int off = (ks - 16) * 32 + quad * 8;
                ahi[0] = *(const short8*)(h2hi + nrow * 136 + off);
                ahi[1] = *(const short8*)(h2hi + (16 + nrow) * 136 + off);
                alo[0] = *(const short8*)(h2lo + nrow * 136 + off);
                alo[1] = *(const short8*)(h2lo + (16 + nrow) * 136 + off);
            }
            const unsigned short* bb = B2 + ks * 32768;
            short8 bh[4], bl[4];
            #pragma unroll
            for (int g = 0; g < 4; ++g) {
                bh[g] = *(const short8*)(bb + g * 1024);
                bl[g] = *(const short8*)(bb + g * 1024 + 512);
            }
            #pragma unroll
            for (int g = 0; g < 4; ++g)
                #pragma unroll
                for (int mt = 0; mt < 2; ++mt) {
                    a2[mt][g] = __builtin_amdgcn_mfma_f32_16x16x32_bf16(ahi[mt], bh[g], a2[mt][g], 0, 0, 0);
                    a2[mt][g] = __builtin_amdgcn_mfma_f32_16x16x32_bf16(alo[mt], bh[g], a2[mt][g], 0, 0, 0);
                    a2[mt][g] = __builtin_amdgcn_mfma_f32_16x16x32_bf16(ahi[mt], bl[g], a2[mt][g], 0, 0, 0);
                }
        }
        __syncthreads();   // D0: reads of h2(t-1)/h1 complete
        #pragma unroll
        for (int mt = 0; mt < 2; ++mt)
            #pragma unroll
            for (int r = 0; r < 4; ++r) {
                float I = sigf(a2[mt][0][r]);
                float F = sigf(a2[mt][1][r]);
                float G = tanhfast(a2[mt][2][r]);
                float O = sigf(a2[mt][3][r]);
                float c = F * c2[mt][r] + I * G;
                c2[mt][r] = c;
                float h = O * tanhfast(c);
                int m = mt * 16 + quad * 4 + r;
                int u = wv * 16 + nrow;
                unsigned short hh = f2b(h);
                h2hi[m * 136 + u] = hh;
                h2lo[m * 136 + u] = f2b(h - b2f(hh));
            }
        __syncthreads();   // D: h2(t) visible

        // ================= L3 (k = [relu(h2) 128 ; h3 64], 6 ksteps) =================
        f32x4 a3[4];
        #pragma unroll
        for (int g = 0; g < 4; ++g) {
            float b = b3v[g];
            f32x4 v = {b, b, b, b};
            a3[g] = v;
        }

        #pragma unroll 1
        for (int kk = 0; kk < 6; ++kk) {
            int ks = rev ? (5 - kk) : kk;
            short8 ahi, alo;
            if (ks < 4) {
                int off = ks * 32 + quad * 8;
                short8 a  = *(const short8*)(h2hi + (mt3 * 16 + nrow) * 136 + off);
                short8 al = *(const short8*)(h2lo + (mt3 * 16 + nrow) * 136 + off);
                short8 msk = a >> 15;
                ahi = a & ~msk;
                alo = al & ~msk;
            } else {
                int off = (ks - 4) * 32 + quad * 8;
                ahi = *(const short8*)(h3hi + (mt3 * 16 + nrow) * 72 + off);
                alo = *(const short8*)(h3lo + (mt3 * 16 + nrow) * 72 + off);
            }
            const unsigned short* bb = B3 + ks * 16384;
            short8 bh[4], bl[4];
            #pragma unroll
            for (int g = 0; g < 4; ++g) {
                bh[g] = *(const short8*)(bb + g * 1024);
                bl[g] = *(const short8*)(bb + g * 1024 + 512);
            }
            #pragma unroll
            for (int g = 0; g < 4; ++g) {
                a3[g] = __builtin_amdgcn_mfma_f32_16x16x32_bf16(ahi, bh[g], a3[g], 0, 0, 0);
                a3[g] = __builtin_amdgcn_mfma_f32_16x16x32_bf16(alo, bh[g], a3[g], 0, 0, 0);
                a3[g] = __builtin_amdgcn_mfma_f32_16x16x32_bf16(ahi, bl[g], a3[g], 0, 0, 0);
            }
        }
        __syncthreads();   // reads of h3(t-1) complete
        #pragma unroll
        for (int r = 0; r < 4; ++r) {
            float I = sigf(a3[0][r]);
            float F = sigf(a3[1][r]);
            float G = tanhfast(a3[2][r]);
            float O = sigf(a3[3][r]);
            float c = F * c3[r] + I * G;
            c3[r] = c;
            float h = O * tanhfast(c);
            int m = mt3 * 16 + quad * 4 + r;
            int u = (wv & 3) * 16 + nrow;
            unsigned short hh = f2b(h);
            h3hi[m * 72 + u] = hh;
            h3lo[m * 72 + u] = f2b(h - b2f(hh));
            Y3[(size_t)(gr0 + m) * 1920 + t * 64 + u] = fmaxf(h, 0.0f);
        }
        __syncthreads();   // E: h3(t) visible before next step
    }
}

// FC head, 16 rows/WG: d staged in LDS (stride 1932: 16B-aligned, bank-spread),
// weights broadcast across the 16 row-lanes -> Wf1 traffic 1024*7.4MB -> 256*... 64x less.
// a1/a2/a3 overlay the d buffer after fc1 (accs held in registers across the barrier).
__global__ __launch_bounds__(512) void head_kernel(
    const float* __restrict__ Y3,
    const float* __restrict__ Wf1, const float* __restrict__ bf1,
    const float* __restrict__ Wf2, const float* __restrict__ bf2,
    const float* __restrict__ Wf3, const float* __restrict__ bf3,
    const float* __restrict__ Wf4, const float* __restrict__ bf4,
    float* __restrict__ out)
{
    extern __shared__ float hds[];
    float* ds = hds;                 // [16][1932] during fc1
    float* a1 = hds;                 // [16][972]  after fc1 (overlay)
    float* a2 = a1 + 16 * 972;       // [16][492]
    float* a3 = a2 + 16 * 492;       // [16][16]

    const int tid = threadIdx.x;
    const int r0  = blockIdx.x * 16;
    const int r   = tid & 15;
    const int og  = tid >> 4;        // 0..31

    for (int e = tid; e < 16 * 1920; e += 512) {
        const int b = e / 1920;
        const int j = e - b * 1920;
        const float v1 = Y3[(size_t)(r0 + b) * 1920 + j];
        const float v2 = Y3[(size_t)(r0 + b + NB) * 1920 + j];
        ds[b * 1932 + j] = fabsf(v1 - v2);
    }
    __syncthreads();

    // fc1: 1920 -> 960 (each thread: 30 outputs o = og + 32*m), accs in regs
    float acc1[30];
    #pragma unroll 1
    for (int m = 0; m < 30; ++m) {
        const int o = og + 32 * m;
        float acc = bf1[o];
        const float4* wr = (const float4*)(Wf1 + (size_t)o * 1920);
        const float4* dv = (const float4*)(ds + r * 1932);
        #pragma unroll 4
        for (int kc = 0; kc < 480; ++kc) {
            const float4 d4 = dv[kc];
            const float4 w4 = wr[kc];
            acc += d4.x * w4.x + d4.y * w4.y + d4.z * w4.z + d4.w * w4.w;
        }
        acc1[m] = fmaxf(acc, 0.0f);
    }
    __syncthreads();               // all reads of ds done
    #pragma unroll
    for (int m = 0; m < 30; ++m) a1[r * 972 + og + 32 * m] = acc1[m];
    __syncthreads();

    // fc2: 960 -> 480 (each thread: 15 outputs)
    float acc2[15];
    #pragma unroll 1
    for (int m = 0; m < 15; ++m) {
        const int o = og + 32 * m;
        float acc = bf2[o];
        const float4* wr = (const float4*)(Wf2 + (size_t)o * 960);
        const float4* av = (const float4*)(a1 + r * 972);
        #pragma unroll 4
        for (int kc = 0; kc < 240; ++kc) {
            const float4 d4 = av[kc];
            const float4 w4 = wr[kc];
            acc += d4.x * w4.x + d4.y * w4.y + d4.z * w4.z + d4.w * w4.w;
        }
        acc2[m] = fmaxf(acc, 0.0f);
    }
    __syncthreads();
    #pragma unroll
    for (int m = 0; m < 15; ++m) a2[r * 492 + og + 32 * m] = acc2[m];
    __syncthreads();

    // fc3: 480 -> 16
    if (tid < 256) {
        const int rr = tid >> 4;
        const int o  = tid & 15;
        float acc = bf3[o];
        const float4* wr = (const float4*)(Wf3 + (size_t)o * 480);
        const float4* av = (const float4*)(a2 + rr * 492);
        #pragma unroll 4
        for (int kc = 0; kc < 120; ++kc) {
            const float4 d4 = av[kc];
            const float4 w4 = wr[kc];
            acc += d4.x * w4.x + d4.y * w4.y + d4.z * w4.z + d4.w * w4.w;
        }
        a3[rr * 16 + o] = fmaxf(acc, 0.0f);
    }
    __syncthreads();

    // fc4: 16 -> 1
    if (tid < 16) {
        float acc = bf4[0];
        #pragma unroll
        for (int k = 0; k < 16; ++k) acc += a3[tid * 16 + k] * Wf4[k];
        out[r0 + tid] = acc;
    }
}

extern "C" void kernel_launch(void* const* d_in, const int* in_sizes, int n_in,
                              void* d_out, int out_size, void* d_ws, size_t ws_size,
                              hipStream_t stream) {
    const float* x1   = (const float*)d_in[0];
    const float* x2   = (const float*)d_in[1];
    const float* Wih1 = (const float*)d_in[2];
    const float* Whh1 = (const float*)d_in[3];
    const float* b1   = (const float*)d_in[4];
    const float* Wih2 = (const float*)d_in[5];
    const float* Whh2 = (const float*)d_in[6];
    const float* b2   = (const float*)d_in[7];
    const float* Wih3 = (const float*)d_in[8];
    const float* Whh3 = (const float*)d_in[9];
    const float* b3   = (const float*)d_in[10];
    const float* Wf1  = (const float*)d_in[11];
    const float* bf1  = (const float*)d_in[12];
    const float* Wf2  = (const float*)d_in[13];
    const float* bf2  = (const float*)d_in[14];
    const float* Wf3  = (const float*)d_in[15];
    const float* bf3  = (const float*)d_in[16];
    const float* Wf4  = (const float*)d_in[17];
    const float* bf4  = (const float*)d_in[18];

    float* wsf = (float*)d_ws;
    float* Y3 = wsf;                                           // 15,728,640 f32
    unsigned short* l1w = (unsigned short*)(wsf + 15728640);   // 2,359,296 us
    unsigned short* l2w = l1w + 2359296;                       //   655,360 us
    unsigned short* l3w = l2w + 655360;                        //    98,304 us
    float* out = (float*)d_out;

    prep_w<<<(2359296 + 255) / 256, 256, 0, stream>>>(Wih1, Whh1, l1w, 512, 58, 64, 512, 32, 18);
    prep_w<<<(655360  + 255) / 256, 256, 0, stream>>>(Wih2, Whh2, l2w, 128, 512, 512, 128, 8, 20);
    prep_w<<<(98304   + 255) / 256, 256, 0, stream>>>(Wih3, Whh3, l3w, 64, 128, 128, 64, 4, 6);

    hipFuncSetAttribute((const void*)lstm3_mfma,
                        hipFuncAttributeMaxDynamicSharedMemorySize, 102400);
    lstm3_mfma<<<256, 512, 102400, stream>>>(x1, x2, l1w, l2w, l3w, b1, b2, b3, Y3);

    hipFuncSetAttribute((const void*)head_kernel,
                        hipFuncAttributeMaxDynamicSharedMemorySize, 16 * 1932 * 4);
    head_kernel<<<NB / 16, 512, 16 * 1932 * 4, stream>>>(Y3, Wf1, bf1, Wf2, bf2,
                                                         Wf3, bf3, Wf4, bf4, out);
}

// Round 5
// 4156.483 us; speedup vs baseline: 1.3277x; 1.3277x over previous
//
#include <hip/hip_runtime.h>

#define NTIME 30
#define NB 4096

typedef __attribute__((ext_vector_type(8))) short short8;
typedef __attribute__((ext_vector_type(4))) float f32x4;
typedef __attribute__((ext_vector_type(16))) float f32x16;

__device__ __forceinline__ unsigned short f2b(float f) {
    unsigned int u = __float_as_uint(f);
    u = u + 0x7FFFu + ((u >> 16) & 1u);        // RNE to bf16
    return (unsigned short)(u >> 16);
}
__device__ __forceinline__ float b2f(unsigned short s) {
    return __uint_as_float(((unsigned int)s) << 16);
}
__device__ __forceinline__ float sigf(float x)     { return 1.0f / (1.0f + __expf(-x)); }
__device__ __forceinline__ float tanhfast(float x) { return 1.0f - 2.0f / (__expf(2.0f * x) + 1.0f); }

// ---- L1 weight pack: 32x32x16 B-frags, bf16 hi/lo planes.
// B-frag: lane holds B[k = (lane>>5)*8 + j][n = lane&31], j=0..7 (k-slot map cancels vs A).
// out[(((s*16 + w)*4 + g)*2 + plane)*512 + lane*8 + j]; k axis = [x 0..64 | h1 0..512], s<36.
__global__ __launch_bounds__(256) void prep_w32(const float* __restrict__ Wih,
                                                const float* __restrict__ Whh,
                                                unsigned short* __restrict__ out)
{
    int e = blockIdx.x * 256 + threadIdx.x;
    if (e >= 36 * 65536) return;
    int j     = e & 7;
    int lane  = (e >> 3) & 63;
    int plane = (e >> 9) & 1;
    int g     = (e >> 10) & 3;
    int w     = (e >> 12) & 15;
    int s     = e >> 16;
    int n = lane & 31, kh = lane >> 5;
    int unit = w * 32 + n;
    int k = s * 16 + kh * 8 + j;
    int row = g * 512 + unit;
    float v = 0.0f;
    if (k < 64) { if (k < 58) v = Wih[row * 58 + k]; }
    else        { v = Whh[row * 512 + (k - 64)]; }
    unsigned short hi = f2b(v);
    out[e] = plane ? f2b(v - b2f(hi)) : hi;
}

// ---- L2/L3 weight pack: 16x16x32 B-frags (as rounds 2-4, validated layout).
// out[(((s*CG + cg)*4 + g)*2 + plane)*512 + lane*8 + j]
__global__ __launch_bounds__(256) void prep_w16(const float* __restrict__ Wih,
                                                const float* __restrict__ Whh,
                                                unsigned short* __restrict__ out,
                                                int H, int KI, int KIp, int KH, int CG, int KS)
{
    int e = blockIdx.x * 256 + threadIdx.x;
    if (e >= KS * CG * 4096) return;
    int j     = e & 7;
    int lane  = (e >> 3) & 63;
    int plane = (e >> 9) & 1;
    int g     = (e >> 10) & 3;
    int rest  = e >> 12;
    int cg = rest % CG;
    int s  = rest / CG;
    int n = lane & 15, q = lane >> 4;
    int unit = cg * 16 + n;
    int k = s * 32 + q * 8 + j;
    int row = g * H + unit;
    float v = 0.0f;
    if (k < KIp) { if (k < KI) v = Wih[row * KI + k]; }
    else         { v = Whh[row * KH + (k - KIp)]; }
    unsigned short hi = f2b(v);
    out[e] = plane ? f2b(v - b2f(hi)) : hi;
}

// ---- Head weight transposes (o-fastest float4-of-k blocks for 1KB coalesced wave loads)
// WT1[kc][o] = float4{ Wf1[o][4kc..4kc+3] }, o padded to 1024 with zeros. kc<480.
__global__ __launch_bounds__(256) void pack_wt1(const float* __restrict__ Wf1, float4* __restrict__ WT1)
{
    int e = blockIdx.x * 256 + threadIdx.x;
    if (e >= 480 * 1024) return;
    int kc = e >> 10, o = e & 1023;
    float4 v = {0.0f, 0.0f, 0.0f, 0.0f};
    if (o < 960) {
        const float* p = Wf1 + (size_t)o * 1920 + kc * 4;
        v.x = p[0]; v.y = p[1]; v.z = p[2]; v.w = p[3];
    }
    WT1[e] = v;
}
// WT2[kc][o] = float4{ Wf2[o][4kc..4kc+3] }, o padded to 512, k padded 960->1024. kc<256.
__global__ __launch_bounds__(256) void pack_wt2(const float* __restrict__ Wf2, float4* __restrict__ WT2)
{
    int e = blockIdx.x * 256 + threadIdx.x;
    if (e >= 256 * 512) return;
    int kc = e >> 9, o = e & 511;
    float4 v = {0.0f, 0.0f, 0.0f, 0.0f};
    if (o < 480) {
        int k = kc * 4;
        v.x = (k + 0 < 960) ? Wf2[(size_t)o * 960 + k + 0] : 0.0f;
        v.y = (k + 1 < 960) ? Wf2[(size_t)o * 960 + k + 1] : 0.0f;
        v.z = (k + 2 < 960) ? Wf2[(size_t)o * 960 + k + 2] : 0.0f;
        v.w = (k + 3 < 960) ? Wf2[(size_t)o * 960 + k + 3] : 0.0f;
    }
    WT2[e] = v;
}

// ---- Fused Siamese 3-layer LSTM. 256 WGs x 1024 thr (16 waves, 4/SIMD), 129KB LDS.
// Rows 0-15 = branch x1 samples, 16-31 = branch x2 (same samples) -> d computed in-WG.
// L1: 32x32x16 MFMA, wave owns 32 units x 4 gate-tiles (acc 4 x f32x16 = 64 regs), no dup fetch.
// L2/L3: 16x16x32, mt-twin waves duplicate B loads (L1-absorbed).
__global__ __launch_bounds__(1024, 4) void lstm3_v2(
    const float* __restrict__ x1, const float* __restrict__ x2,
    const unsigned short* __restrict__ l1w, const unsigned short* __restrict__ l2w,
    const unsigned short* __restrict__ l3w,
    const float* __restrict__ b1, const float* __restrict__ b2, const float* __restrict__ b3,
    float* __restrict__ dbuf)
{
    extern __shared__ unsigned short sm[];
    unsigned short* h1hi = sm;                    // [32][520]
    unsigned short* h1lo = h1hi + 32 * 520;
    unsigned short* h2hi = h1lo + 32 * 520;       // [2][32][136]
    unsigned short* h2lo = h2hi + 2 * 32 * 136;
    unsigned short* h3hi = h2lo + 2 * 32 * 136;   // [2][32][72]
    unsigned short* h3lo = h3hi + 2 * 32 * 72;
    unsigned short* xhi  = h3lo + 2 * 32 * 72;    // [32][72]
    unsigned short* xlo  = xhi  + 32 * 72;

    const int tid  = threadIdx.x;
    const int wv   = tid >> 6;
    const int lane = tid & 63;
    const int wg   = blockIdx.x;
    const int samp0 = wg * 16;

    // zero all LDS state (64512 ushorts)
    {
        unsigned int* p = (unsigned int*)sm;
        for (int i = tid; i < 64512 / 2; i += 1024) p[i] = 0u;
    }

    // L1 lane mapping (32x32)
    const int n1 = lane & 31;
    const int kh = lane >> 5;
    const int u1 = wv * 32 + n1;
    // L2/L3 lane mapping (16x16)
    const int n2   = lane & 15;
    const int quad = lane >> 4;
    const int mt2  = wv >> 3, cg2 = wv & 7;
    const int u2   = cg2 * 16 + n2;
    const int row2 = mt2 * 16 + n2;
    const int mt3  = (wv >> 2) & 1, cg3 = wv & 3;
    const int u3   = cg3 * 16 + n2;
    const int row3 = mt3 * 16 + n2;

    float c1[16], c2[4], c3[4];
    #pragma unroll
    for (int r = 0; r < 16; ++r) c1[r] = 0.0f;
    #pragma unroll
    for (int r = 0; r < 4; ++r) { c2[r] = 0.0f; c3[r] = 0.0f; }

    const unsigned short* B1p = l1w + wv * 4096 + lane * 8;
    const unsigned short* B2p = l2w + cg2 * 4096 + lane * 8;
    const unsigned short* B3p = l3w + cg3 * 4096 + lane * 8;

    __syncthreads();

    int cur = 0;
    #pragma unroll 1
    for (int t = 0; t < NTIME; ++t) {
        const bool rev = (t & 1);
        const int nxt = cur ^ 1;

        // stage x_t: rows 0-15 from x1, 16-31 from x2 (layout [B,58,30]); pad K to 64
        for (int e = tid; e < 2048; e += 1024) {
            int b = e >> 6, f = e & 63;
            const float* __restrict__ xp = (b < 16) ? x1 : x2;
            float v = (f < 58) ? xp[(samp0 + (b & 15)) * 1740 + f * 30 + t] : 0.0f;
            unsigned short hi = f2b(v);
            xhi[b * 72 + f] = hi;
            xlo[b * 72 + f] = f2b(v - b2f(hi));
        }
        __syncthreads();   // A

        // ============ L1: 32x32x16, k = [x 64 | h1 512], 36 ksteps ============
        f32x16 A0, A1, A2, A3;
        {
            float bg0 = b1[u1], bg1 = b1[512 + u1], bg2 = b1[1024 + u1], bg3 = b1[1536 + u1];
            #pragma unroll
            for (int r = 0; r < 16; ++r) { A0[r] = bg0; A1[r] = bg1; A2[r] = bg2; A3[r] = bg3; }
        }
        #pragma unroll 1
        for (int ss = 0; ss < 36; ++ss) {
            int s = rev ? (35 - ss) : ss;
            short8 ahi, alo;
            if (s < 4) {
                int off = s * 16 + kh * 8;
                ahi = *(const short8*)(xhi + n1 * 72 + off);
                alo = *(const short8*)(xlo + n1 * 72 + off);
            } else {
                int off = (s - 4) * 16 + kh * 8;
                ahi = *(const short8*)(h1hi + n1 * 520 + off);
                alo = *(const short8*)(h1lo + n1 * 520 + off);
            }
            const unsigned short* bb = B1p + s * 65536;
            short8 bh0 = *(const short8*)(bb);
            short8 bl0 = *(const short8*)(bb + 512);
            short8 bh1 = *(const short8*)(bb + 1024);
            short8 bl1 = *(const short8*)(bb + 1536);
            short8 bh2 = *(const short8*)(bb + 2048);
            short8 bl2 = *(const short8*)(bb + 2560);
            short8 bh3 = *(const short8*)(bb + 3072);
            short8 bl3 = *(const short8*)(bb + 3584);
            A0 = __builtin_amdgcn_mfma_f32_32x32x16_bf16(ahi, bh0, A0, 0, 0, 0);
            A1 = __builtin_amdgcn_mfma_f32_32x32x16_bf16(ahi, bh1, A1, 0, 0, 0);
            A2 = __builtin_amdgcn_mfma_f32_32x32x16_bf16(ahi, bh2, A2, 0, 0, 0);
            A3 = __builtin_amdgcn_mfma_f32_32x32x16_bf16(ahi, bh3, A3, 0, 0, 0);
            A0 = __builtin_amdgcn_mfma_f32_32x32x16_bf16(alo, bh0, A0, 0, 0, 0);
            A1 = __builtin_amdgcn_mfma_f32_32x32x16_bf16(alo, bh1, A1, 0, 0, 0);
            A2 = __builtin_amdgcn_mfma_f32_32x32x16_bf16(alo, bh2, A2, 0, 0, 0);
            A3 = __builtin_amdgcn_mfma_f32_32x32x16_bf16(alo, bh3, A3, 0, 0, 0);
            A0 = __builtin_amdgcn_mfma_f32_32x32x16_bf16(ahi, bl0, A0, 0, 0, 0);
            A1 = __builtin_amdgcn_mfma_f32_32x32x16_bf16(ahi, bl1, A1, 0, 0, 0);
            A2 = __builtin_amdgcn_mfma_f32_32x32x16_bf16(ahi, bl2, A2, 0, 0, 0);
            A3 = __builtin_amdgcn_mfma_f32_32x32x16_bf16(ahi, bl3, A3, 0, 0, 0);
        }
        __syncthreads();   // B: all reads of h1(t-1)/x done
        #pragma unroll
        for (int r = 0; r < 16; ++r) {
            float I = sigf(A0[r]);
            float F = sigf(A1[r]);
            float G = tanhfast(A2[r]);
            float O = sigf(A3[r]);
            float c = F * c1[r] + I * G;
            c1[r] = c;
            float h = O * tanhfast(c);
            int row = (r & 3) + 8 * (r >> 2) + 4 * kh;   // verified 32x32 C-map
            unsigned short hh = f2b(h);
            h1hi[row * 520 + u1] = hh;
            h1lo[row * 520 + u1] = f2b(h - b2f(hh));
        }
        __syncthreads();   // C: h1(t) visible

        // ============ L2: 16x16x32, k = [relu(h1) 512 | h2 128], 20 ksteps ============
        f32x4 a20, a21, a22, a23;
        {
            float bg0 = b2[u2], bg1 = b2[128 + u2], bg2 = b2[256 + u2], bg3 = b2[384 + u2];
            a20 = (f32x4){bg0, bg0, bg0, bg0};
            a21 = (f32x4){bg1, bg1, bg1, bg1};
            a22 = (f32x4){bg2, bg2, bg2, bg2};
            a23 = (f32x4){bg3, bg3, bg3, bg3};
        }
        #pragma unroll 1
        for (int ss = 0; ss < 20; ++ss) {
            int s = rev ? (19 - ss) : ss;
            short8 ahi, alo;
            if (s < 16) {
                int off = s * 32 + quad * 8;
                short8 a  = *(const short8*)(h1hi + row2 * 520 + off);
                short8 al = *(const short8*)(h1lo + row2 * 520 + off);
                short8 msk = a >> 15;
                ahi = a & ~msk;
                alo = al & ~msk;
            } else {
                int off = (s - 16) * 32 + quad * 8;
                ahi = *(const short8*)(h2hi + cur * 4352 + row2 * 136 + off);
                alo = *(const short8*)(h2lo + cur * 4352 + row2 * 136 + off);
            }
            const unsigned short* bb = B2p + s * 32768;
            short8 bh0 = *(const short8*)(bb);
            short8 bl0 = *(const short8*)(bb + 512);
            short8 bh1 = *(const short8*)(bb + 1024);
            short8 bl1 = *(const short8*)(bb + 1536);
            short8 bh2 = *(const short8*)(bb + 2048);
            short8 bl2 = *(const short8*)(bb + 2560);
            short8 bh3 = *(const short8*)(bb + 3072);
            short8 bl3 = *(const short8*)(bb + 3584);
            a20 = __builtin_amdgcn_mfma_f32_16x16x32_bf16(ahi, bh0, a20, 0, 0, 0);
            a21 = __builtin_amdgcn_mfma_f32_16x16x32_bf16(ahi, bh1, a21, 0, 0, 0);
            a22 = __builtin_amdgcn_mfma_f32_16x16x32_bf16(ahi, bh2, a22, 0, 0, 0);
            a23 = __builtin_amdgcn_mfma_f32_16x16x32_bf16(ahi, bh3, a23, 0, 0, 0);
            a20 = __builtin_amdgcn_mfma_f32_16x16x32_bf16(alo, bh0, a20, 0, 0, 0);
            a21 = __builtin_amdgcn_mfma_f32_16x16x32_bf16(alo, bh1, a21, 0, 0, 0);
            a22 = __builtin_amdgcn_mfma_f32_16x16x32_bf16(alo, bh2, a22, 0, 0, 0);
            a23 = __builtin_amdgcn_mfma_f32_16x16x32_bf16(alo, bh3, a23, 0, 0, 0);
            a20 = __builtin_amdgcn_mfma_f32_16x16x32_bf16(ahi, bl0, a20, 0, 0, 0);
            a21 = __builtin_amdgcn_mfma_f32_16x16x32_bf16(ahi, bl1, a21, 0, 0, 0);
            a22 = __builtin_amdgcn_mfma_f32_16x16x32_bf16(ahi, bl2, a22, 0, 0, 0);
            a23 = __builtin_amdgcn_mfma_f32_16x16x32_bf16(ahi, bl3, a23, 0, 0, 0);
        }
        // write h2[nxt] (disjoint from concurrent reads of h2[cur]/h1)
        #pragma unroll
        for (int r = 0; r < 4; ++r) {
            float I = sigf(a20[r]);
            float F = sigf(a21[r]);
            float G = tanhfast(a22[r]);
            float O = sigf(a23[r]);
            float c = F * c2[r] + I * G;
            c2[r] = c;
            float h = O * tanhfast(c);
            int row = mt2 * 16 + quad * 4 + r;
            unsigned short hh = f2b(h);
            h2hi[nxt * 4352 + row * 136 + u2] = hh;
            h2lo[nxt * 4352 + row * 136 + u2] = f2b(h - b2f(hh));
        }
        __syncthreads();   // D: h2(t) visible

        // ============ L3: 16x16x32, k = [relu(h2) 128 | h3 64], 6 ksteps (waves 0-7) ====
        if (wv < 8) {
            f32x4 a30, a31, a32, a33;
            {
                float bg0 = b3[u3], bg1 = b3[64 + u3], bg2 = b3[128 + u3], bg3 = b3[192 + u3];
                a30 = (f32x4){bg0, bg0, bg0, bg0};
                a31 = (f32x4){bg1, bg1, bg1, bg1};
                a32 = (f32x4){bg2, bg2, bg2, bg2};
                a33 = (f32x4){bg3, bg3, bg3, bg3};
            }
            #pragma unroll 1
            for (int ss = 0; ss < 6; ++ss) {
                int s = rev ? (5 - ss) : ss;
                short8 ahi, alo;
                if (s < 4) {
                    int off = s * 32 + quad * 8;
                    short8 a  = *(const short8*)(h2hi + nxt * 4352 + row3 * 136 + off);
                    short8 al = *(const short8*)(h2lo + nxt * 4352 + row3 * 136 + off);
                    short8 msk = a >> 15;
                    ahi = a & ~msk;
                    alo = al & ~msk;
                } else {
                    int off = (s - 4) * 32 + quad * 8;
                    ahi = *(const short8*)(h3hi + cur * 2304 + row3 * 72 + off);
                    alo = *(const short8*)(h3lo + cur * 2304 + row3 * 72 + off);
                }
                const unsigned short* bb = B3p + s * 16384;
                short8 bh0 = *(const short8*)(bb);
                short8 bl0 = *(const short8*)(bb + 512);
                short8 bh1 = *(const short8*)(bb + 1024);
                short8 bl1 = *(const short8*)(bb + 1536);
                short8 bh2 = *(const short8*)(bb + 2048);
                short8 bl2 = *(const short8*)(bb + 2560);
                short8 bh3 = *(const short8*)(bb + 3072);
                short8 bl3 = *(const short8*)(bb + 3584);
                a30 = __builtin_amdgcn_mfma_f32_16x16x32_bf16(ahi, bh0, a30, 0, 0, 0);
                a31 = __builtin_amdgcn_mfma_f32_16x16x32_bf16(ahi, bh1, a31, 0, 0, 0);
                a32 = __builtin_amdgcn_mfma_f32_16x16x32_bf16(ahi, bh2, a32, 0, 0, 0);
                a33 = __builtin_amdgcn_mfma_f32_16x16x32_bf16(ahi, bh3, a33, 0, 0, 0);
                a30 = __builtin_amdgcn_mfma_f32_16x16x32_bf16(alo, bh0, a30, 0, 0, 0);
                a31 = __builtin_amdgcn_mfma_f32_16x16x32_bf16(alo, bh1, a31, 0, 0, 0);
                a32 = __builtin_amdgcn_mfma_f32_16x16x32_bf16(alo, bh2, a32, 0, 0, 0);
                a33 = __builtin_amdgcn_mfma_f32_16x16x32_bf16(alo, bh3, a33, 0, 0, 0);
                a30 = __builtin_amdgcn_mfma_f32_16x16x32_bf16(ahi, bl0, a30, 0, 0, 0);
                a31 = __builtin_amdgcn_mfma_f32_16x16x32_bf16(ahi, bl1, a31, 0, 0, 0);
                a32 = __builtin_amdgcn_mfma_f32_16x16x32_bf16(ahi, bl2, a32, 0, 0, 0);
                a33 = __builtin_amdgcn_mfma_f32_16x16x32_bf16(ahi, bl3, a33, 0, 0, 0);
            }
            #pragma unroll
            for (int r = 0; r < 4; ++r) {
                float I = sigf(a30[r]);
                float F = sigf(a31[r]);
                float G = tanhfast(a32[r]);
                float O = sigf(a33[r]);
                float c = F * c3[r] + I * G;
                c3[r] = c;
                float h = O * tanhfast(c);
                int row = mt3 * 16 + quad * 4 + r;
                unsigned short hh = f2b(h);
                h3hi[nxt * 2304 + row * 72 + u3] = hh;
                h3lo[nxt * 2304 + row * 72 + u3] = f2b(h - b2f(hh));
            }
        }
        __syncthreads();   // E: h3(t) visible

        // d = |relu(h3_x1) - relu(h3_x2)|, streamed to global (head input)
        {
            int b = tid >> 6, u = tid & 63;
            float ha = b2f(h3hi[nxt * 2304 + b * 72 + u]) + b2f(h3lo[nxt * 2304 + b * 72 + u]);
            float hb = b2f(h3hi[nxt * 2304 + (16 + b) * 72 + u]) + b2f(h3lo[nxt * 2304 + (16 + b) * 72 + u]);
            dbuf[(size_t)(samp0 + b) * 1920 + t * 64 + u] = fabsf(fmaxf(ha, 0.0f) - fmaxf(hb, 0.0f));
        }
        cur = nxt;
    }
}

// ---- FC head v2: 256 WGs x 512 thr x 16 samples. d staged in LDS; weights read as
// o-fastest float4 blocks (1KB coalesced per wave-instr); d via LDS broadcast.
__global__ __launch_bounds__(512) void head_v2(
    const float* __restrict__ dg,
    const float4* __restrict__ WT1, const float* __restrict__ bf1,
    const float4* __restrict__ WT2, const float* __restrict__ bf2,
    const float* __restrict__ Wf3, const float* __restrict__ bf3,
    const float* __restrict__ Wf4, const float* __restrict__ bf4,
    float* __restrict__ out)
{
    extern __shared__ float hds[];
    float* ds = hds;                  // [16][1928] during fc1
    float* a1 = hds;                  // [16][1032] overlay after fc1
    float* a2 = a1 + 16 * 1032;       // [16][520]
    float* a3 = a2 + 16 * 520;        // [16][16]

    const int tid = threadIdx.x;
    const int samp0 = blockIdx.x * 16;

    // stage d (float4, fully coalesced)
    for (int e = tid; e < 16 * 480; e += 512) {
        int b = e / 480, jc = e - b * 480;
        ((float4*)(ds + b * 1928))[jc] = ((const float4*)(dg + (size_t)(samp0 + b) * 1920))[jc];
    }
    __syncthreads();

    // fc1: 1920 -> 960 (padded 1024). Thread: 2 outs (oA, oA+64) x 16 rows.
    const int w = tid >> 6, lane = tid & 63;
    const int oA = w * 128 + lane, oB = oA + 64;
    float accA[16], accB[16];
    {
        float bA = (oA < 960) ? bf1[oA] : 0.0f;
        float bB = (oB < 960) ? bf1[oB] : 0.0f;
        #pragma unroll
        for (int r = 0; r < 16; ++r) { accA[r] = bA; accB[r] = bB; }
    }
    #pragma unroll 2
    for (int kc = 0; kc < 480; ++kc) {
        float4 wA = WT1[kc * 1024 + oA];
        float4 wB = WT1[kc * 1024 + oB];
        #pragma unroll
        for (int r = 0; r < 16; ++r) {
            float4 d4 = ((const float4*)(ds + r * 1928))[kc];   // wave broadcast
            accA[r] += d4.x * wA.x + d4.y * wA.y + d4.z * wA.z + d4.w * wA.w;
            accB[r] += d4.x * wB.x + d4.y * wB.y + d4.z * wB.z + d4.w * wB.w;
        }
    }
    __syncthreads();   // ds dead
    #pragma unroll
    for (int r = 0; r < 16; ++r) {
        a1[r * 1032 + oA] = fmaxf(accA[r], 0.0f);
        a1[r * 1032 + oB] = fmaxf(accB[r], 0.0f);
    }
    __syncthreads();

    // fc2: 960(pad 1024) -> 480 (pad 512). Thread: 1 out x 16 rows.
    const int o2 = tid;
    float acc2[16];
    {
        float b = (o2 < 480) ? bf2[o2] : 0.0f;
        #pragma unroll
        for (int r = 0; r < 16; ++r) acc2[r] = b;
    }
    #pragma unroll 2
    for (int kc = 0; kc < 256; ++kc) {
        float4 w4 = WT2[kc * 512 + o2];
        #pragma unroll
        for (int r = 0; r < 16; ++r) {
            float4 a4 = ((const float4*)(a1 + r * 1032))[kc];   // wave broadcast
            acc2[r] += a4.x * w4.x + a4.y * w4.y + a4.z * w4.z + a4.w * w4.w;
        }
    }
    #pragma unroll
    for (int r = 0; r < 16; ++r) a2[r * 520 + o2] = fmaxf(acc2[r], 0.0f);   // pad region unread
    __syncthreads();

    // fc3: 480 -> 16
    if (tid < 256) {
        int o = tid & 15, r = tid >> 4;
        float acc = bf3[o];
        const float4* wr = (const float4*)(Wf3 + (size_t)o * 480);
        const float4* av = (const float4*)(a2 + r * 520);
        #pragma unroll 4
        for (int kc = 0; kc < 120; ++kc) {
            float4 a4 = av[kc];
            float4 w4 = wr[kc];
            acc += a4.x * w4.x + a4.y * w4.y + a4.z * w4.z + a4.w * w4.w;
        }
        a3[r * 16 + o] = fmaxf(acc, 0.0f);
    }
    __syncthreads();

    // fc4: 16 -> 1
    if (tid < 16) {
        float acc = bf4[0];
        #pragma unroll
        for (int k = 0; k < 16; ++k) acc += a3[tid * 16 + k] * Wf4[k];
        out[samp0 + tid] = acc;
    }
}

extern "C" void kernel_launch(void* const* d_in, const int* in_sizes, int n_in,
                              void* d_out, int out_size, void* d_ws, size_t ws_size,
                              hipStream_t stream) {
    const float* x1   = (const float*)d_in[0];
    const float* x2   = (const float*)d_in[1];
    const float* Wih1 = (const float*)d_in[2];
    const float* Whh1 = (const float*)d_in[3];
    const float* b1   = (const float*)d_in[4];
    const float* Wih2 = (const float*)d_in[5];
    const float* Whh2 = (const float*)d_in[6];
    const float* b2   = (const float*)d_in[7];
    const float* Wih3 = (const float*)d_in[8];
    const float* Whh3 = (const float*)d_in[9];
    const float* b3   = (const float*)d_in[10];
    const float* Wf1  = (const float*)d_in[11];
    const float* bf1  = (const float*)d_in[12];
    const float* Wf2  = (const float*)d_in[13];
    const float* bf2  = (const float*)d_in[14];
    const float* Wf3  = (const float*)d_in[15];
    const float* bf3  = (const float*)d_in[16];
    const float* Wf4  = (const float*)d_in[17];
    const float* bf4  = (const float*)d_in[18];

    float* wsf = (float*)d_ws;
    float* dbuf = wsf;                                         // 4096*1920 = 7,864,320 f32
    unsigned short* l1w = (unsigned short*)(wsf + 7864320);    // 36*65536  = 2,359,296 us
    unsigned short* l2w = l1w + 2359296;                       // 20*8*4096 =   655,360 us
    unsigned short* l3w = l2w + 655360;                        //  6*4*4096 =    98,304 us
    float4* WT1 = (float4*)(wsf + 9420800);                    // 480*1024 float4
    float4* WT2 = WT1 + 480 * 1024;                            // 256*512  float4
    float* out = (float*)d_out;

    prep_w32<<<(36 * 65536) / 256, 256, 0, stream>>>(Wih1, Whh1, l1w);
    prep_w16<<<(20 * 8 * 4096) / 256, 256, 0, stream>>>(Wih2, Whh2, l2w, 128, 512, 512, 128, 8, 20);
    prep_w16<<<(6 * 4 * 4096) / 256, 256, 0, stream>>>(Wih3, Whh3, l3w, 64, 128, 128, 64, 4, 6);
    pack_wt1<<<(480 * 1024) / 256, 256, 0, stream>>>(Wf1, WT1);
    pack_wt2<<<(256 * 512) / 256, 256, 0, stream>>>(Wf2, WT2);

    hipFuncSetAttribute((const void*)lstm3_v2,
                        hipFuncAttributeMaxDynamicSharedMemorySize, 129024);
    lstm3_v2<<<256, 1024, 129024, stream>>>(x1, x2, l1w, l2w, l3w, b1, b2, b3, dbuf);

    hipFuncSetAttribute((const void*)head_v2,
                        hipFuncAttributeMaxDynamicSharedMemorySize, 16 * 1928 * 4);
    head_v2<<<256, 512, 16 * 1928 * 4, stream>>>(dbuf, WT1, bf1, WT2, bf2,
                                                 Wf3, bf3, Wf4, bf4, out);
}